// Round 5
// baseline (380.997 us; speedup 1.0000x reference)
//
#include <hip/hip_runtime.h>

#define N_NODES 50000
#define N_EDGES 800000
#define CH 128
#define NOUT 10
#define NUM_GRAPHS 128
#define SCAN_B 256
#define N_SCAN_BLOCKS ((N_NODES + SCAN_B - 1) / SCAN_B)   // 196
#define POOL_CHUNK 50
#define GR 64   // gemm rows per block

// ---------- zero fills ----------
__global__ void k_zero_int(int* p, int n) {
    int i = blockIdx.x * blockDim.x + threadIdx.x;
    if (i < n) p[i] = 0;
}
__global__ void k_zero4(float4* p, int n4) {
    int i = blockIdx.x * blockDim.x + threadIdx.x;
    if (i < n4) p[i] = make_float4(0.f, 0.f, 0.f, 0.f);
}

// ---------- CSR build ----------
__global__ void k_hist(const int* __restrict__ dst, int* __restrict__ cnt) {
    int e = blockIdx.x * blockDim.x + threadIdx.x;
    if (e < N_EDGES) atomicAdd(&cnt[dst[e]], 1);
}

__global__ __launch_bounds__(SCAN_B) void k_scan1(const int* __restrict__ cnt,
                                                  int* __restrict__ row_start,
                                                  int* __restrict__ bsum) {
    __shared__ int s[SCAN_B];
    int tid = threadIdx.x;
    int i = blockIdx.x * SCAN_B + tid;
    int v = (i < N_NODES) ? cnt[i] : 0;
    s[tid] = v;
    __syncthreads();
    for (int off = 1; off < SCAN_B; off <<= 1) {
        int t = (tid >= off) ? s[tid - off] : 0;
        __syncthreads();
        s[tid] += t;
        __syncthreads();
    }
    if (i < N_NODES) row_start[i] = s[tid] - v;
    if (tid == SCAN_B - 1) bsum[blockIdx.x] = s[tid];
}

__global__ __launch_bounds__(SCAN_B) void k_scan2(int* __restrict__ bsum) {
    __shared__ int s[SCAN_B];
    int tid = threadIdx.x;
    int v = (tid < N_SCAN_BLOCKS) ? bsum[tid] : 0;
    s[tid] = v;
    __syncthreads();
    for (int off = 1; off < SCAN_B; off <<= 1) {
        int t = (tid >= off) ? s[tid - off] : 0;
        __syncthreads();
        s[tid] += t;
        __syncthreads();
    }
    if (tid < N_SCAN_BLOCKS) bsum[tid] = s[tid] - v;
}

__global__ __launch_bounds__(SCAN_B) void k_scan3(int* __restrict__ row_start,
                                                  const int* __restrict__ bsum,
                                                  int* __restrict__ fill_pos,
                                                  const int* __restrict__ cnt,
                                                  float* __restrict__ dinv) {
    int i = blockIdx.x * SCAN_B + threadIdx.x;
    if (i < N_NODES) {
        int rs = row_start[i] + bsum[blockIdx.x];
        row_start[i] = rs;
        fill_pos[i] = rs;
        dinv[i] = rsqrtf((float)(cnt[i] + 1));
    }
}

// fill (src, dinv[src]) pairs
__global__ void k_fill(const int* __restrict__ src, const int* __restrict__ dst,
                       int* __restrict__ fill_pos, const float* __restrict__ dinv,
                       int2* __restrict__ csr_uw) {
    int e = blockIdx.x * blockDim.x + threadIdx.x;
    if (e < N_EDGES) {
        int u = src[e];
        int pos = atomicAdd(&fill_pos[dst[e]], 1);
        csr_uw[pos] = make_int2(u, __float_as_int(dinv[u]));
    }
}

// ---------- register-tiled GEMM: Y[N,128] = X[N,128] @ W[128,128] ----------
__global__ __launch_bounds__(256) void k_gemm_rt(const float* __restrict__ X,
                                                 const float* __restrict__ W,
                                                 float* __restrict__ Y) {
    __shared__ float xs[GR][CH];
    const int tid = threadIdx.x;
    const int lane = tid & 31;
    const int g = tid >> 5;
    const int row0 = blockIdx.x * GR;

    const float4* Xv = (const float4*)X;
    #pragma unroll
    for (int i = 0; i < 8; ++i) {
        int f = tid + i * 256;
        int r = f >> 5;
        float4 val = make_float4(0.f, 0.f, 0.f, 0.f);
        if (row0 + r < N_NODES) val = Xv[(size_t)row0 * 32 + f];
        ((float4*)xs)[f] = val;
    }
    __syncthreads();

    float4 acc[8];
    #pragma unroll
    for (int i = 0; i < 8; ++i) acc[i] = make_float4(0.f, 0.f, 0.f, 0.f);

    const float4* Wv = (const float4*)W;
    #pragma unroll 8
    for (int k = 0; k < CH; ++k) {
        float4 w = Wv[k * 32 + lane];
        #pragma unroll
        for (int i = 0; i < 8; ++i) {
            float xv = xs[g * 8 + i][k];
            acc[i].x = fmaf(xv, w.x, acc[i].x);
            acc[i].y = fmaf(xv, w.y, acc[i].y);
            acc[i].z = fmaf(xv, w.z, acc[i].z);
            acc[i].w = fmaf(xv, w.w, acc[i].w);
        }
    }

    #pragma unroll
    for (int i = 0; i < 8; ++i) {
        int row = row0 + g * 8 + i;
        if (row < N_NODES) ((float4*)Y)[(size_t)row * 32 + lane] = acc[i];
    }
}

// ---------- gather-aggregate: one wave per node, 2 edges per load ----------
// Lanes split into 2 halves of 32; half h loads edge (j+h)'s row as float4.
// One global_load_dwordx4 covers 2 edge-rows; 4 loads in flight = 8 edges.
__global__ __launch_bounds__(256) void k_gather3(const float* __restrict__ t,
                                                 const int2* __restrict__ csr_uw,
                                                 const int* __restrict__ row_start,
                                                 const int* __restrict__ cnt,
                                                 const float* __restrict__ dinv,
                                                 const float* __restrict__ b,
                                                 float* __restrict__ h) {
    const int wid = threadIdx.x >> 6;
    const int lane = threadIdx.x & 63;
    const int half = lane >> 5;          // 0 or 1
    const int sub = lane & 31;           // float4 slot within row
    const int v = blockIdx.x * 4 + wid;  // 12500 * 4 = 50000

    const int start = row_start[v];
    const int len = cnt[v];
    const float dv = dinv[v];
    const float4* tv = (const float4*)t;

    float4 a0 = {0,0,0,0}, a1 = {0,0,0,0}, a2 = {0,0,0,0}, a3 = {0,0,0,0};

    for (int base = 0; base < len; base += 64) {
        int m = len - base; if (m > 64) m = 64;
        int2 uw = make_int2(0, 0);
        if (lane < m) uw = csr_uw[start + base + lane];   // coalesced 8B/lane

        int j = 0;
        for (; j + 7 < m; j += 8) {
            int   u0 = __shfl(uw.x, j     + half);
            float w0 = __int_as_float(__shfl(uw.y, j     + half));
            int   u1 = __shfl(uw.x, j + 2 + half);
            float w1 = __int_as_float(__shfl(uw.y, j + 2 + half));
            int   u2 = __shfl(uw.x, j + 4 + half);
            float w2 = __int_as_float(__shfl(uw.y, j + 4 + half));
            int   u3 = __shfl(uw.x, j + 6 + half);
            float w3 = __int_as_float(__shfl(uw.y, j + 6 + half));
            float4 t0 = tv[(size_t)u0 * 32 + sub];
            float4 t1 = tv[(size_t)u1 * 32 + sub];
            float4 t2 = tv[(size_t)u2 * 32 + sub];
            float4 t3 = tv[(size_t)u3 * 32 + sub];
            a0.x = fmaf(w0, t0.x, a0.x); a0.y = fmaf(w0, t0.y, a0.y);
            a0.z = fmaf(w0, t0.z, a0.z); a0.w = fmaf(w0, t0.w, a0.w);
            a1.x = fmaf(w1, t1.x, a1.x); a1.y = fmaf(w1, t1.y, a1.y);
            a1.z = fmaf(w1, t1.z, a1.z); a1.w = fmaf(w1, t1.w, a1.w);
            a2.x = fmaf(w2, t2.x, a2.x); a2.y = fmaf(w2, t2.y, a2.y);
            a2.z = fmaf(w2, t2.z, a2.z); a2.w = fmaf(w2, t2.w, a2.w);
            a3.x = fmaf(w3, t3.x, a3.x); a3.y = fmaf(w3, t3.y, a3.y);
            a3.z = fmaf(w3, t3.z, a3.z); a3.w = fmaf(w3, t3.w, a3.w);
        }
        for (; j + 1 < m; j += 2) {
            int   u = __shfl(uw.x, j + half);
            float w = __int_as_float(__shfl(uw.y, j + half));
            float4 tt = tv[(size_t)u * 32 + sub];
            a0.x = fmaf(w, tt.x, a0.x); a0.y = fmaf(w, tt.y, a0.y);
            a0.z = fmaf(w, tt.z, a0.z); a0.w = fmaf(w, tt.w, a0.w);
        }
        if (j < m) {   // last single edge: half 1 contributes 0
            int   u = __shfl(uw.x, j);
            float w = (half == 0) ? __int_as_float(__shfl(uw.y, j)) : 0.f;
            float4 tt = tv[(size_t)u * 32 + sub];
            a0.x = fmaf(w, tt.x, a0.x); a0.y = fmaf(w, tt.y, a0.y);
            a0.z = fmaf(w, tt.z, a0.z); a0.w = fmaf(w, tt.w, a0.w);
        }
    }

    float4 s;
    s.x = a0.x + a1.x + a2.x + a3.x;
    s.y = a0.y + a1.y + a2.y + a3.y;
    s.z = a0.z + a1.z + a2.z + a3.z;
    s.w = a0.w + a1.w + a2.w + a3.w;
    s.x += __shfl_xor(s.x, 32);
    s.y += __shfl_xor(s.y, 32);
    s.z += __shfl_xor(s.z, 32);
    s.w += __shfl_xor(s.w, 32);

    if (half == 0) {
        float4 self = tv[(size_t)v * 32 + sub];
        float4 bb = ((const float4*)b)[sub];
        float4 o;
        o.x = fmaxf(fmaf(dv, fmaf(dv, self.x, s.x), bb.x), 0.f);
        o.y = fmaxf(fmaf(dv, fmaf(dv, self.y, s.y), bb.y), 0.f);
        o.z = fmaxf(fmaf(dv, fmaf(dv, self.z, s.z), bb.z), 0.f);
        o.w = fmaxf(fmaf(dv, fmaf(dv, self.w, s.w), bb.w), 0.f);
        ((float4*)h)[(size_t)v * 32 + sub] = o;
    }
}

// ---------- segmented mean pool (batch sorted) ----------
__global__ __launch_bounds__(128) void k_pool2(const float* __restrict__ h,
                                               const int* __restrict__ batch,
                                               float* __restrict__ psum) {
    const int c = threadIdx.x;
    const int v0 = blockIdx.x * POOL_CHUNK;
    __shared__ int bg[POOL_CHUNK];
    if (c < POOL_CHUNK) bg[c] = batch[v0 + c];
    __syncthreads();

    float acc = 0.f;
    int g = bg[0];
    #pragma unroll 5
    for (int j = 0; j < POOL_CHUNK; ++j) {
        int bgj = bg[j];
        float val = h[(size_t)(v0 + j) * CH + c];
        if (bgj != g) {
            atomicAdd(&psum[g * CH + c], acc);
            acc = 0.f;
            g = bgj;
        }
        acc += val;
    }
    atomicAdd(&psum[g * CH + c], acc);
}

// ---------- per-graph inverse counts (batch sorted) ----------
__global__ __launch_bounds__(NUM_GRAPHS) void k_counts(const int* __restrict__ batch,
                                                       float* __restrict__ pinv) {
    int g = threadIdx.x;
    int lo = 0, hi = N_NODES;
    while (lo < hi) { int mid = (lo + hi) >> 1; if (batch[mid] < g) lo = mid + 1; else hi = mid; }
    int start = lo;
    lo = 0; hi = N_NODES;
    while (lo < hi) { int mid = (lo + hi) >> 1; if (batch[mid] < g + 1) lo = mid + 1; else hi = mid; }
    int n = lo - start;
    pinv[g] = 1.0f / fmaxf((float)n, 1.0f);
}

// ---------- classifier head ----------
__global__ __launch_bounds__(128) void k_classify(const float* __restrict__ psum,
                                                  const float* __restrict__ pinv,
                                                  const float* __restrict__ Wc,
                                                  const float* __restrict__ bc,
                                                  float* __restrict__ out) {
    __shared__ float p[CH];
    int g = blockIdx.x;
    int tid = threadIdx.x;
    p[tid] = psum[g * CH + tid] * pinv[g];
    __syncthreads();
    if (tid < NOUT) {
        float acc = bc[tid];
        #pragma unroll 4
        for (int k = 0; k < CH; ++k) acc += p[k] * Wc[k * NOUT + tid];
        out[g * NOUT + tid] = acc;
    }
}

extern "C" void kernel_launch(void* const* d_in, const int* in_sizes, int n_in,
                              void* d_out, int out_size, void* d_ws, size_t ws_size,
                              hipStream_t stream) {
    const float* x     = (const float*)d_in[0];
    const int*   ei    = (const int*)d_in[1];
    const int*   batch = (const int*)d_in[2];
    const float* W1    = (const float*)d_in[3];
    const float* b1    = (const float*)d_in[4];
    const float* W2    = (const float*)d_in[5];
    const float* b2    = (const float*)d_in[6];
    const float* Wc    = (const float*)d_in[7];
    const float* bc    = (const float*)d_in[8];
    float* out = (float*)d_out;

    const int* src = ei;
    const int* dst = ei + N_EDGES;

    float* dinv      = (float*)d_ws;                       // N
    int*   cnt       = (int*)(dinv + N_NODES);             // N
    int*   row_start = cnt + N_NODES;                      // N
    int*   fill_pos  = row_start + N_NODES;                // N
    int*   bsum      = fill_pos + N_NODES;                 // 256
    int2*  csr_uw    = (int2*)(bsum + 256);                // E int2
    float* tbuf      = (float*)(csr_uw + N_EDGES);         // N*CH
    float* hbuf      = tbuf + (size_t)N_NODES * CH;        // N*CH
    float* psum      = hbuf + (size_t)N_NODES * CH;        // G*CH
    float* pinv      = psum + NUM_GRAPHS * CH;             // G

    // ---- CSR build + norm ----
    k_zero_int<<<(N_NODES + 255) / 256, 256, 0, stream>>>(cnt, N_NODES);
    k_hist<<<(N_EDGES + 255) / 256, 256, 0, stream>>>(dst, cnt);
    k_scan1<<<N_SCAN_BLOCKS, SCAN_B, 0, stream>>>(cnt, row_start, bsum);
    k_scan2<<<1, SCAN_B, 0, stream>>>(bsum);
    k_scan3<<<N_SCAN_BLOCKS, SCAN_B, 0, stream>>>(row_start, bsum, fill_pos, cnt, dinv);
    k_fill<<<(N_EDGES + 255) / 256, 256, 0, stream>>>(src, dst, fill_pos, dinv, csr_uw);

    // ---- conv1 ----
    k_gemm_rt<<<(N_NODES + GR - 1) / GR, 256, 0, stream>>>(x, W1, tbuf);
    k_gather3<<<N_NODES / 4, 256, 0, stream>>>(tbuf, csr_uw, row_start, cnt, dinv, b1, hbuf);

    // ---- conv2 ----
    k_gemm_rt<<<(N_NODES + GR - 1) / GR, 256, 0, stream>>>(hbuf, W2, tbuf);
    k_gather3<<<N_NODES / 4, 256, 0, stream>>>(tbuf, csr_uw, row_start, cnt, dinv, b2, hbuf);

    // ---- pool + head ----
    k_zero4<<<(NUM_GRAPHS * CH / 4 + 255) / 256, 256, 0, stream>>>(
        (float4*)psum, NUM_GRAPHS * CH / 4);
    k_counts<<<1, NUM_GRAPHS, 0, stream>>>(batch, pinv);
    k_pool2<<<N_NODES / POOL_CHUNK, 128, 0, stream>>>(hbuf, batch, psum);
    k_classify<<<NUM_GRAPHS, 128, 0, stream>>>(psum, pinv, Wc, bc, out);
}